// Round 4
// baseline (310.392 us; speedup 1.0000x reference)
//
#include <hip/hip_runtime.h>
#include <hip/hip_bf16.h>

// Problem constants
#define BB 2
#define LL 5000
#define CIN 256
#define CLOI 128
#define HH 256
#define WW 256
#define HWP (HH*WW)
#define NPTS0 32
#define NPTS1 8
#define PLANES 64
#define EPSV 1e-5f

// workspace layout (bytes)
#define X_BYTES   ((size_t)BB * HWP * CLOI * 2)            // 33,554,432: fc1 map bf16 channel-last
#define XS_BYTES  ((size_t)BB * LL * 1024 * 2)             // (dead region; offsets kept stable)
#define W1S_OFF   (X_BYTES + XS_BYTES)                     // 8192 bf16 = 16384 B   [16kg][64m][8]
#define W2S_OFF   (W1S_OFF + 16384)                        // 12288 bf16 = 24576 B  [3dt][8kg][64m][8]
#define W3S_OFF   (W2S_OFF + 24576)                        // 8192 bf16 = 16384 B   [8kg][128m][8]
#define B1P_OFF   (W3S_OFF + 16384)                        // 64 f32
#define B2P_OFF   (B1P_OFF + 256)                          // 64 f32
#define S1_OFF    (B2P_OFF + 256)                          // 128 f32
#define T1_OFF    (S1_OFF + 512)                           // 128 f32
#define W0S_OFF   (T1_OFF + 512)                           // fc1_w bf16 swizzled [32grp][128m][8] = 65536 B

typedef unsigned int uint;
typedef unsigned short ushort;
typedef __attribute__((ext_vector_type(8))) short short8;
typedef __attribute__((ext_vector_type(4))) float f32x4;

__device__ __forceinline__ float bf2f(ushort u) {
    uint v = ((uint)u) << 16;
    return __uint_as_float(v);
}
__device__ __forceinline__ ushort f2bf(float f) {
    uint x = __float_as_uint(f);
    uint r = (x + 0x7fffu + ((x >> 16) & 1u)) >> 16;   // RNE
    return (ushort)r;
}
__device__ __forceinline__ uint pack2(float a, float b) {
    return (uint)f2bf(a) | ((uint)f2bf(b) << 16);
}

// ---------------------------------------------------------------------------
// Kernel A: fc1 1x1 conv as bf16 MFMA GEMM.  (unchanged — memory-bound)
// ---------------------------------------------------------------------------
__global__ __launch_bounds__(256) void fc1_kernel(
    const float* __restrict__ feature, const ushort* __restrict__ w0s,
    const float* __restrict__ fc1_b, ushort* __restrict__ xout)
{
    __shared__ ushort sF[32 * 64 * 8];   // [grp(k/8)][px][j] bf16, 32 KB

    int tid = threadIdx.x;
    int tile = blockIdx.x;               // 0..2047
    int b = tile >> 10;
    int p0 = (tile & 1023) << 6;
    int wv = tid >> 6, lane = tid & 63;
    int q = lane >> 4, ln = lane & 15;

    // preload A-frags: afr[kg][mt], k = kg*32 + q*8 + j, m = wv*32 + mt*16 + ln
    short8 afr[8][2];
#pragma unroll
    for (int kg = 0; kg < 8; kg++)
#pragma unroll
        for (int mt = 0; mt < 2; mt++)
            afr[kg][mt] = *(const short8*)(w0s + ((size_t)((kg * 4 + q) * 128 + wv * 32 + mt * 16 + ln)) * 8);

    // stage feature tile -> bf16 LDS (B-frag layout)
    const float* fb = feature + (size_t)b * CIN * HWP + p0;
    int g_ = tid >> 4;                   // 0..15 (channel group within pass)
    int qd = tid & 15;                   // pixel quad
#pragma unroll
    for (int s = 0; s < 2; s++) {
        int g = s * 16 + g_;             // channel group 0..31 (8 ch each)
        const float* src = fb + (size_t)(g * 8) * HWP + qd * 4;
        float4 rv[8];
#pragma unroll
        for (int j = 0; j < 8; j++) rv[j] = *(const float4*)(src + (size_t)j * HWP);
#pragma unroll
        for (int i = 0; i < 4; i++) {
            uint4 u;
            u.x = pack2(((const float*)&rv[0])[i], ((const float*)&rv[1])[i]);
            u.y = pack2(((const float*)&rv[2])[i], ((const float*)&rv[3])[i]);
            u.z = pack2(((const float*)&rv[4])[i], ((const float*)&rv[5])[i]);
            u.w = pack2(((const float*)&rv[6])[i], ((const float*)&rv[7])[i]);
            *(uint4*)(&sF[(g * 64 + qd * 4 + i) * 8]) = u;
        }
    }
    __syncthreads();

    const f32x4 fzero = { 0.f, 0.f, 0.f, 0.f };
    f32x4 acc[2][4];
#pragma unroll
    for (int mt = 0; mt < 2; mt++)
#pragma unroll
        for (int nt = 0; nt < 4; nt++) acc[mt][nt] = fzero;

#pragma unroll
    for (int kg = 0; kg < 8; kg++) {
#pragma unroll
        for (int nt = 0; nt < 4; nt++) {
            short8 bfr = *(short8*)(&sF[((kg * 4 + q) * 64 + nt * 16 + ln) * 8]);
            acc[0][nt] = __builtin_amdgcn_mfma_f32_16x16x32_bf16(afr[kg][0], bfr, acc[0][nt], 0, 0, 0);
            acc[1][nt] = __builtin_amdgcn_mfma_f32_16x16x32_bf16(afr[kg][1], bfr, acc[1][nt], 0, 0, 0);
        }
    }

    // epilogue: bias + pack + store. o = wv*32 + mt*16 + q*4 + r, p = p0 + nt*16 + ln
    float bias[8];
    *(float4*)bias       = *(const float4*)(fc1_b + wv * 32 + q * 4);
    *(float4*)(bias + 4) = *(const float4*)(fc1_b + wv * 32 + 16 + q * 4);
    ushort* xrow = xout + (size_t)b * HWP * CLOI;
#pragma unroll
    for (int mt = 0; mt < 2; mt++)
#pragma unroll
        for (int nt = 0; nt < 4; nt++) {
            uint2 u;
            u.x = pack2(acc[mt][nt][0] + bias[mt * 4 + 0], acc[mt][nt][1] + bias[mt * 4 + 1]);
            u.y = pack2(acc[mt][nt][2] + bias[mt * 4 + 2], acc[mt][nt][3] + bias[mt * 4 + 3]);
            *(uint2*)(xrow + (size_t)(p0 + nt * 16 + ln) * CLOI + wv * 32 + mt * 16 + q * 4) = u;
        }
}

// ---------------------------------------------------------------------------
// Prep kernel (unchanged)
// ---------------------------------------------------------------------------
__global__ __launch_bounds__(256) void prep_kernel(
    const float* __restrict__ conv1_w, const float* __restrict__ conv1_b,
    const float* __restrict__ bn2_g, const float* __restrict__ bn2_b,
    const float* __restrict__ bn2_m, const float* __restrict__ bn2_v,
    const float* __restrict__ conv2_w, const float* __restrict__ conv2_b,
    const float* __restrict__ bn3_g, const float* __restrict__ bn3_b,
    const float* __restrict__ bn3_m, const float* __restrict__ bn3_v,
    const float* __restrict__ conv3_w,
    const float* __restrict__ bn1_g, const float* __restrict__ bn1_b,
    const float* __restrict__ bn1_m, const float* __restrict__ bn1_v,
    const float* __restrict__ fc1_w,
    ushort* __restrict__ w1s, ushort* __restrict__ w2s, ushort* __restrict__ w3s,
    float* __restrict__ b1p, float* __restrict__ b2p,
    float* __restrict__ s1o, float* __restrict__ t1o,
    ushort* __restrict__ w0s)
{
    int idx = blockIdx.x * 256 + threadIdx.x;
    if (idx < 8192) {   // W1s [16kg][64m][8], fold s2
        int kg = idx >> 9, rem = idx & 511, m = rem >> 3, j = rem & 7;
        int c = kg * 8 + j;
        float s2 = bn2_g[m] * rsqrtf(bn2_v[m] + EPSV);
        w1s[idx] = f2bf(conv1_w[m * 128 + c] * s2);
    }
    if (idx < 12288) {  // W2s [3dt][8kg][64m][8], fold s3
        int dt = idx >> 12, rem = idx & 4095;
        int kg = rem >> 9, m = (rem >> 3) & 63, j = rem & 7;
        int i = kg * 8 + j;
        float s3 = bn3_g[m] * rsqrtf(bn3_v[m] + EPSV);
        w2s[idx] = f2bf(conv2_w[m * 192 + i * 3 + dt] * s3);
    }
    if (idx < 8192) {   // W3s [8kg][128m][8]
        int kg = idx >> 10, rem = idx & 1023, m = rem >> 3, j = rem & 7;
        w3s[idx] = f2bf(conv3_w[m * 64 + kg * 8 + j]);
    }
    if (idx < 32768) {  // W0s [32grp][128m][8] from fc1_w [128m][256c]
        int grp = idx >> 10, rem = idx & 1023, m = rem >> 3, j = rem & 7;
        w0s[idx] = f2bf(fc1_w[m * CIN + grp * 8 + j]);
    }
    if (idx < 64) {
        float s2 = bn2_g[idx] * rsqrtf(bn2_v[idx] + EPSV);
        b1p[idx] = conv1_b[idx] * s2 + bn2_b[idx] - bn2_m[idx] * s2;
        float s3 = bn3_g[idx] * rsqrtf(bn3_v[idx] + EPSV);
        b2p[idx] = conv2_b[idx] * s3 + bn3_b[idx] - bn3_m[idx] * s3;
    }
    if (idx < 128) {
        float s1 = bn1_g[idx] * rsqrtf(bn1_v[idx] + EPSV);
        s1o[idx] = s1;
        t1o[idx] = bn1_b[idx] - bn1_m[idx] * s1;
    }
}

// ---------------------------------------------------------------------------
// Fused kernel v3: attack the latency-bound gather (R3 counters: MfmaUtil
// 1.8%, VALUBusy 26%, hbm 18%, Occ 36% -> nothing saturated = latency).
//  (a) TLP: sIdx/sWt (8 KB, dead after gather barrier) UNION'd with sB2
//      (8 KB, first written after it).  LDS 33.8 -> 25.6 KB -> 6 blocks/CU
//      (24 waves/CU) with __launch_bounds__(256,6) (VGPR cap ~84).
//  (b) MLP: gather issues 16 corner loads (4 points x 4 corners) into named
//      regs before consuming any -> >=16 outstanding loads/wave vs ~4.
// Phase timeline: setup writes sIdx/sWt | barrier | gather reads them,
// writes sH1 | barrier | conv1 reads sH1, writes sB2 (same bytes as
// sIdx/sWt — now dead) | barrier | xs->sH1, preload bfr2 | barrier |
// conv2 -> sB2 | barrier | conv3 + residual + fc2.
// ---------------------------------------------------------------------------
__global__ __launch_bounds__(256, 6) void sample_head_kernel(
    const ushort* __restrict__ x, const float* __restrict__ lines,
    const ushort* __restrict__ w1s, const ushort* __restrict__ w2s,
    const ushort* __restrict__ w3s,
    const float* __restrict__ b1p, const float* __restrict__ b2p,
    const float* __restrict__ s1g, const float* __restrict__ t1g,
    const float* __restrict__ conv3_b,
    const float* __restrict__ fc2_w, const float* __restrict__ fc2_b,
    float* __restrict__ out)
{
    __shared__ ushort sH1[8192];             // 16 KB: h1, then xs (XOR-swizzled)
    __shared__ __align__(16) char sU[8192];  // 8 KB union: {sIdx 4K + sWt 4K} then sB2
    __shared__ float sB1[64], sB2b[64], sB3b[128];

    int4*   sIdx = (int4*)sU;                // [l*32 + j]
    float4* sWt  = (float4*)(sU + 4096);     // [l*32 + j]
    ushort* sB2  = (ushort*)sU;              // [8kg][64col][8] (after gather)

    int tid = threadIdx.x;
    int wv = tid >> 6, lane = tid & 63;
    int q = lane >> 4, ln = lane & 15;
    int L0 = blockIdx.x * 8;
    int b = L0 / LL;                 // blocks never straddle images
    int colg = wv * 16 + ln;

    if (tid < 128) sB3b[tid] = conv3_b[tid];
    if (tid < 64)  { sB1[tid] = b1p[tid]; sB2b[tid] = b2p[tid]; }

    // per-thread bn1 params for channels 2*lane, 2*lane+1 (L1-resident)
    float s1a = s1g[2 * lane], s1c = s1g[2 * lane + 1];
    float t1a = t1g[2 * lane], t1c = t1g[2 * lane + 1];

    // ---- setup: 8 lines x 32 points, full 256-thread utilization ----
    {
        int l = tid >> 5, j = tid & 31;
        float lam = (float)j * (1.0f / 31.0f);
        const float* lp = lines + (size_t)(L0 + l) * 4;
        float e0x = lp[0], e0y = lp[1], e1x = lp[2], e1y = lp[3];
        float px = e0x * lam + e1x * (1.f - lam) - 0.5f;
        float py = e0y * lam + e1y * (1.f - lam) - 0.5f;
        float px0 = fminf(fmaxf(floorf(px), 0.f), 255.f);
        float py0 = fminf(fmaxf(floorf(py), 0.f), 255.f);
        float px1 = fminf(px0 + 1.f, 255.f);
        float py1 = fminf(py0 + 1.f, 255.f);
        int ix0 = (int)px0, iy0 = (int)py0, ix1 = (int)px1, iy1 = (int)py1;
        int4 iv; float4 wt;
        iv.x = ix0 * WW + iy0;
        iv.y = ix1 * WW + iy0;
        iv.z = ix0 * WW + iy1;
        iv.w = ix1 * WW + iy1;
        wt.x = (px1 - px) * (py1 - py);
        wt.y = (px - px0) * (py1 - py);
        wt.z = (px1 - px) * (py - py0);
        wt.w = (px - px0) * (py - py0);
        sIdx[l * 32 + j] = iv;
        sWt[l * 32 + j]  = wt;
    }
    __syncthreads();

    // ---- gather + maxpool: xs -> regs, h1 = relu(bn1(xs)) -> sH1 ----
    const uint* xb = (const uint*)(x + (size_t)b * HWP * CLOI);
    int kg = lane >> 2;              // channel group 0..15
    int j2 = (lane & 3) * 2;         // position within group
    int swz = (kg & 7) << 3;         // ushort-index XOR swizzle

    uint xsu[8][2];
#pragma unroll
    for (int l = 0; l < 8; l++) {
        float mA0, mA1;              // running max for the half-pool
#pragma unroll
        for (int jh = 0; jh < 2; jh++) {
            // batch-issue 16 loads (4 points x 4 corners) before consuming
            uint u[4][4];
#pragma unroll
            for (int jj = 0; jj < 4; jj++) {
                int4 iv = sIdx[l * 32 + wv * 8 + jh * 4 + jj];
                u[jj][0] = xb[(size_t)iv.x * 64 + lane];
                u[jj][1] = xb[(size_t)iv.y * 64 + lane];
                u[jj][2] = xb[(size_t)iv.z * 64 + lane];
                u[jj][3] = xb[(size_t)iv.w * 64 + lane];
            }
            float m0 = -INFINITY, m1 = -INFINITY;
#pragma unroll
            for (int jj = 0; jj < 4; jj++) {
                float4 wt = sWt[l * 32 + wv * 8 + jh * 4 + jj];
                float v0 = bf2f((ushort)(u[jj][0] & 0xffff)) * wt.x + bf2f((ushort)(u[jj][1] & 0xffff)) * wt.y
                         + bf2f((ushort)(u[jj][2] & 0xffff)) * wt.z + bf2f((ushort)(u[jj][3] & 0xffff)) * wt.w;
                float v1 = bf2f((ushort)(u[jj][0] >> 16)) * wt.x + bf2f((ushort)(u[jj][1] >> 16)) * wt.y
                         + bf2f((ushort)(u[jj][2] >> 16)) * wt.z + bf2f((ushort)(u[jj][3] >> 16)) * wt.w;
                m0 = fmaxf(m0, v0);
                m1 = fmaxf(m1, v1);
            }
            if (jh == 0) { mA0 = m0; mA1 = m1; }
            else {
                xsu[l][0] = pack2(mA0, mA1);
                xsu[l][1] = pack2(m0, m1);
                int col0 = l * 8 + 2 * wv;
                int base0 = (kg * 64 + col0) * 8 + j2;
                float h00 = fmaxf(mA0 * s1a + t1a, 0.f), h10 = fmaxf(mA1 * s1c + t1c, 0.f);
                float h01 = fmaxf(m0 * s1a + t1a, 0.f),  h11 = fmaxf(m1 * s1c + t1c, 0.f);
                *(uint*)(&sH1[base0 ^ swz])       = pack2(h00, h10);
                *(uint*)(&sH1[(base0 + 8) ^ swz]) = pack2(h01, h11);
            }
        }
    }
    __syncthreads();   // gather done: sIdx/sWt dead -> their bytes become sB2

    const short8 bzero = { 0, 0, 0, 0, 0, 0, 0, 0 };
    const f32x4 fzero = { 0.f, 0.f, 0.f, 0.f };

    // ---- conv1: M=64, K=128 (reads sH1 = h1) ----
    f32x4 acc1[4];
#pragma unroll
    for (int mt = 0; mt < 4; mt++) acc1[mt] = fzero;
#pragma unroll
    for (int ks = 0; ks < 4; ks++) {
        int kk = ks * 4 + q;
        short8 bfrag = *(short8*)(&sH1[((kk * 64 + colg) * 8) ^ ((kk & 7) << 3)]);
#pragma unroll
        for (int mt = 0; mt < 4; mt++) {
            short8 a = *(const short8*)(w1s + (kk * 64 + mt * 16 + ln) * 8);
            acc1[mt] = __builtin_amdgcn_mfma_f32_16x16x32_bf16(a, bfrag, acc1[mt], 0, 0, 0);
        }
    }
    // epilogue -> sB2 (linear; overwrites dead sIdx/sWt bytes)
#pragma unroll
    for (int mt = 0; mt < 4; mt++) {
        int m0 = mt * 16 + q * 4;
        float v0 = fmaxf(acc1[mt][0] + sB1[m0 + 0], 0.f);
        float v1 = fmaxf(acc1[mt][1] + sB1[m0 + 1], 0.f);
        float v2 = fmaxf(acc1[mt][2] + sB1[m0 + 2], 0.f);
        float v3 = fmaxf(acc1[mt][3] + sB1[m0 + 3], 0.f);
        uint2 u; u.x = pack2(v0, v1); u.y = pack2(v2, v3);
        *(uint2*)(&sB2[((m0 >> 3) * 64 + colg) * 8 + (m0 & 7)]) = u;
    }
    __syncthreads();   // conv1 done: sH1 (h1) now dead, sB2 (conv1-out) live

    // ---- xs regs -> sH1 (same layout/swizzle the gather used) ----
#pragma unroll
    for (int l = 0; l < 8; l++) {
        int col0 = l * 8 + 2 * wv;
        int base0 = (kg * 64 + col0) * 8 + j2;
        *(uint*)(&sH1[base0 ^ swz])       = xsu[l][0];
        *(uint*)(&sH1[(base0 + 8) ^ swz]) = xsu[l][1];
    }

    // ---- conv2: preload all B-frags from sB2 (3 taps x 2 ks) ----
    int tpos = colg & 7;
    short8 bfr2[3][2];
#pragma unroll
    for (int dt = 0; dt < 3; dt++) {
        int tsh = tpos + dt - 1;
        bool valid = ((unsigned)tsh < 8u);
        int colr = colg + dt - 1;
        colr = colr < 0 ? 0 : (colr > 63 ? 63 : colr);
#pragma unroll
        for (int ks = 0; ks < 2; ks++) {
            short8 bfrag = *(short8*)(&sB2[((ks * 4 + q) * 64 + colr) * 8]);
            bfr2[dt][ks] = valid ? bfrag : bzero;
        }
    }
    __syncthreads();   // all sB2 reads drained; sB2 free for B3

    // ---- conv2 MFMAs, epilogue B3 -> sB2 (linear) ----
    f32x4 acc2[4];
#pragma unroll
    for (int mt = 0; mt < 4; mt++) acc2[mt] = fzero;
#pragma unroll
    for (int dt = 0; dt < 3; dt++)
#pragma unroll
        for (int ks = 0; ks < 2; ks++) {
            int kk = ks * 4 + q;
#pragma unroll
            for (int mt = 0; mt < 4; mt++) {
                short8 a = *(const short8*)(w2s + dt * 4096 + (kk * 64 + mt * 16 + ln) * 8);
                acc2[mt] = __builtin_amdgcn_mfma_f32_16x16x32_bf16(a, bfr2[dt][ks], acc2[mt], 0, 0, 0);
            }
        }
#pragma unroll
    for (int mt = 0; mt < 4; mt++) {
        int m0 = mt * 16 + q * 4;
        float v0 = fmaxf(acc2[mt][0] + sB2b[m0 + 0], 0.f);
        float v1 = fmaxf(acc2[mt][1] + sB2b[m0 + 1], 0.f);
        float v2 = fmaxf(acc2[mt][2] + sB2b[m0 + 2], 0.f);
        float v3 = fmaxf(acc2[mt][3] + sB2b[m0 + 3], 0.f);
        uint2 u; u.x = pack2(v0, v1); u.y = pack2(v2, v3);
        *(uint2*)(&sB2[((m0 >> 3) * 64 + colg) * 8 + (m0 & 7)]) = u;
    }
    __syncthreads();   // B3 live in sB2; xs live in sH1

    // ---- conv3: M=128, K=64 (reads B3 from sB2, linear) ----
    f32x4 acc3[8];
#pragma unroll
    for (int mt = 0; mt < 8; mt++) acc3[mt] = fzero;
#pragma unroll
    for (int ks = 0; ks < 2; ks++) {
        int kk = ks * 4 + q;
        short8 bfrag = *(short8*)(&sB2[(kk * 64 + colg) * 8]);
#pragma unroll
        for (int mt = 0; mt < 8; mt++) {
            short8 a = *(const short8*)(w3s + (kk * 128 + mt * 16 + ln) * 8);
            acc3[mt] = __builtin_amdgcn_mfma_f32_16x16x32_bf16(a, bfrag, acc3[mt], 0, 0, 0);
        }
    }

    // ---- residual + relu + fc2 (xs from sH1; fc2_w direct from L1) ----
    float p0 = 0.f, p1 = 0.f, p2 = 0.f;
#pragma unroll
    for (int mt = 0; mt < 8; mt++) {
#pragma unroll
        for (int r = 0; r < 4; r++) {
            int m = mt * 16 + q * 4 + r;
            int idx = ((m >> 3) * 512 + colg * 8 + (m & 7)) ^ (((m >> 3) & 7) << 3);
            float xsv = bf2f(sH1[idx]);
            float v = fmaxf(xsv + acc3[mt][r] + sB3b[m], 0.f);
            int fi = m * 8 + tpos;
            p0 += v * fc2_w[fi];
            p1 += v * fc2_w[1024 + fi];
            p2 += v * fc2_w[2048 + fi];
        }
    }
    p0 += __shfl_xor(p0, 32); p1 += __shfl_xor(p1, 32); p2 += __shfl_xor(p2, 32);
    p0 += __shfl_xor(p0, 16); p1 += __shfl_xor(p1, 16); p2 += __shfl_xor(p2, 16);
    p0 += __shfl_xor(p0, 4);  p1 += __shfl_xor(p1, 4);  p2 += __shfl_xor(p2, 4);
    p0 += __shfl_xor(p0, 2);  p1 += __shfl_xor(p1, 2);  p2 += __shfl_xor(p2, 2);
    p0 += __shfl_xor(p0, 1);  p1 += __shfl_xor(p1, 1);  p2 += __shfl_xor(p2, 1);

    if (lane == 0 || lane == 8) {
        int line = L0 + wv * 2 + (lane >> 3);
        out[(size_t)line * 3 + 0] = p0 + fc2_b[0];
        out[(size_t)line * 3 + 1] = p1 + fc2_b[1];
        out[(size_t)line * 3 + 2] = p2 + fc2_b[2];
    }
}

extern "C" void kernel_launch(void* const* d_in, const int* in_sizes, int n_in,
                              void* d_out, int out_size, void* d_ws, size_t ws_size,
                              hipStream_t stream) {
    const float* feature = (const float*)d_in[0];
    const float* lines   = (const float*)d_in[1];
    const float* fc1_w   = (const float*)d_in[2];
    const float* fc1_b   = (const float*)d_in[3];
    const float* bn1_g   = (const float*)d_in[4];
    const float* bn1_b   = (const float*)d_in[5];
    const float* bn1_m   = (const float*)d_in[6];
    const float* bn1_v   = (const float*)d_in[7];
    const float* conv1_w = (const float*)d_in[8];
    const float* conv1_b = (const float*)d_in[9];
    const float* bn2_g   = (const float*)d_in[10];
    const float* bn2_b   = (const float*)d_in[11];
    const float* bn2_m   = (const float*)d_in[12];
    const float* bn2_v   = (const float*)d_in[13];
    const float* conv2_w = (const float*)d_in[14];
    const float* conv2_b = (const float*)d_in[15];
    const float* bn3_g   = (const float*)d_in[16];
    const float* bn3_b   = (const float*)d_in[17];
    const float* bn3_m   = (const float*)d_in[18];
    const float* bn3_v   = (const float*)d_in[19];
    const float* conv3_w = (const float*)d_in[20];
    const float* conv3_b = (const float*)d_in[21];
    const float* fc2_w   = (const float*)d_in[22];
    const float* fc2_b   = (const float*)d_in[23];
    float* out = (float*)d_out;

    char* ws = (char*)d_ws;
    ushort* x_bf = (ushort*)ws;
    ushort* w1s  = (ushort*)(ws + W1S_OFF);
    ushort* w2s  = (ushort*)(ws + W2S_OFF);
    ushort* w3s  = (ushort*)(ws + W3S_OFF);
    float*  b1p  = (float*)(ws + B1P_OFF);
    float*  b2p  = (float*)(ws + B2P_OFF);
    float*  s1g  = (float*)(ws + S1_OFF);
    float*  t1g  = (float*)(ws + T1_OFF);
    ushort* w0s  = (ushort*)(ws + W0S_OFF);

    prep_kernel<<<128, 256, 0, stream>>>(
        conv1_w, conv1_b, bn2_g, bn2_b, bn2_m, bn2_v,
        conv2_w, conv2_b, bn3_g, bn3_b, bn3_m, bn3_v,
        conv3_w, bn1_g, bn1_b, bn1_m, bn1_v, fc1_w,
        w1s, w2s, w3s, b1p, b2p, s1g, t1g, w0s);
    fc1_kernel<<<2048, 256, 0, stream>>>(feature, w0s, fc1_b, x_bf);
    sample_head_kernel<<<BB * LL / 8, 256, 0, stream>>>(
        x_bf, lines, w1s, w2s, w3s, b1p, b2p, s1g, t1g, conv3_b, fc2_w, fc2_b, out);
}

// Round 5
// 289.960 us; speedup vs baseline: 1.0705x; 1.0705x over previous
//
#include <hip/hip_runtime.h>
#include <hip/hip_bf16.h>

// Problem constants
#define BB 2
#define LL 5000
#define CIN 256
#define CLOI 128
#define HH 256
#define WW 256
#define HWP (HH*WW)
#define NPTS0 32
#define NPTS1 8
#define PLANES 64
#define EPSV 1e-5f

// workspace layout (bytes)
#define X_BYTES   ((size_t)BB * HWP * CLOI * 2)            // 33,554,432: fc1 map bf16 channel-last
#define XS_BYTES  ((size_t)BB * LL * 1024 * 2)             // (dead region; offsets kept stable)
#define W1S_OFF   (X_BYTES + XS_BYTES)                     // 8192 bf16 = 16384 B   [16kg][64m][8]
#define W2S_OFF   (W1S_OFF + 16384)                        // 12288 bf16 = 24576 B  [3dt][8kg][64m][8]
#define W3S_OFF   (W2S_OFF + 24576)                        // 8192 bf16 = 16384 B   [8kg][128m][8]
#define B1P_OFF   (W3S_OFF + 16384)                        // 64 f32
#define B2P_OFF   (B1P_OFF + 256)                          // 64 f32
#define S1_OFF    (B2P_OFF + 256)                          // 128 f32
#define T1_OFF    (S1_OFF + 512)                           // 128 f32
#define W0S_OFF   (T1_OFF + 512)                           // fc1_w bf16 swizzled [32grp][128m][8] = 65536 B

typedef unsigned int uint;
typedef unsigned short ushort;
typedef __attribute__((ext_vector_type(8))) short short8;
typedef __attribute__((ext_vector_type(4))) float f32x4;

__device__ __forceinline__ float bf2f(ushort u) {
    uint v = ((uint)u) << 16;
    return __uint_as_float(v);
}
__device__ __forceinline__ ushort f2bf(float f) {
    uint x = __float_as_uint(f);
    uint r = (x + 0x7fffu + ((x >> 16) & 1u)) >> 16;   // RNE
    return (ushort)r;
}
__device__ __forceinline__ uint pack2(float a, float b) {
    return (uint)f2bf(a) | ((uint)f2bf(b) << 16);
}

// ---------------------------------------------------------------------------
// Kernel A: fc1 1x1 conv as bf16 MFMA GEMM.  (unchanged — memory-bound)
// ---------------------------------------------------------------------------
__global__ __launch_bounds__(256) void fc1_kernel(
    const float* __restrict__ feature, const ushort* __restrict__ w0s,
    const float* __restrict__ fc1_b, ushort* __restrict__ xout)
{
    __shared__ ushort sF[32 * 64 * 8];   // [grp(k/8)][px][j] bf16, 32 KB

    int tid = threadIdx.x;
    int tile = blockIdx.x;               // 0..2047
    int b = tile >> 10;
    int p0 = (tile & 1023) << 6;
    int wv = tid >> 6, lane = tid & 63;
    int q = lane >> 4, ln = lane & 15;

    // preload A-frags: afr[kg][mt], k = kg*32 + q*8 + j, m = wv*32 + mt*16 + ln
    short8 afr[8][2];
#pragma unroll
    for (int kg = 0; kg < 8; kg++)
#pragma unroll
        for (int mt = 0; mt < 2; mt++)
            afr[kg][mt] = *(const short8*)(w0s + ((size_t)((kg * 4 + q) * 128 + wv * 32 + mt * 16 + ln)) * 8);

    // stage feature tile -> bf16 LDS (B-frag layout)
    const float* fb = feature + (size_t)b * CIN * HWP + p0;
    int g_ = tid >> 4;                   // 0..15 (channel group within pass)
    int qd = tid & 15;                   // pixel quad
#pragma unroll
    for (int s = 0; s < 2; s++) {
        int g = s * 16 + g_;             // channel group 0..31 (8 ch each)
        const float* src = fb + (size_t)(g * 8) * HWP + qd * 4;
        float4 rv[8];
#pragma unroll
        for (int j = 0; j < 8; j++) rv[j] = *(const float4*)(src + (size_t)j * HWP);
#pragma unroll
        for (int i = 0; i < 4; i++) {
            uint4 u;
            u.x = pack2(((const float*)&rv[0])[i], ((const float*)&rv[1])[i]);
            u.y = pack2(((const float*)&rv[2])[i], ((const float*)&rv[3])[i]);
            u.z = pack2(((const float*)&rv[4])[i], ((const float*)&rv[5])[i]);
            u.w = pack2(((const float*)&rv[6])[i], ((const float*)&rv[7])[i]);
            *(uint4*)(&sF[(g * 64 + qd * 4 + i) * 8]) = u;
        }
    }
    __syncthreads();

    const f32x4 fzero = { 0.f, 0.f, 0.f, 0.f };
    f32x4 acc[2][4];
#pragma unroll
    for (int mt = 0; mt < 2; mt++)
#pragma unroll
        for (int nt = 0; nt < 4; nt++) acc[mt][nt] = fzero;

#pragma unroll
    for (int kg = 0; kg < 8; kg++) {
#pragma unroll
        for (int nt = 0; nt < 4; nt++) {
            short8 bfr = *(short8*)(&sF[((kg * 4 + q) * 64 + nt * 16 + ln) * 8]);
            acc[0][nt] = __builtin_amdgcn_mfma_f32_16x16x32_bf16(afr[kg][0], bfr, acc[0][nt], 0, 0, 0);
            acc[1][nt] = __builtin_amdgcn_mfma_f32_16x16x32_bf16(afr[kg][1], bfr, acc[1][nt], 0, 0, 0);
        }
    }

    // epilogue: bias + pack + store. o = wv*32 + mt*16 + q*4 + r, p = p0 + nt*16 + ln
    float bias[8];
    *(float4*)bias       = *(const float4*)(fc1_b + wv * 32 + q * 4);
    *(float4*)(bias + 4) = *(const float4*)(fc1_b + wv * 32 + 16 + q * 4);
    ushort* xrow = xout + (size_t)b * HWP * CLOI;
#pragma unroll
    for (int mt = 0; mt < 2; mt++)
#pragma unroll
        for (int nt = 0; nt < 4; nt++) {
            uint2 u;
            u.x = pack2(acc[mt][nt][0] + bias[mt * 4 + 0], acc[mt][nt][1] + bias[mt * 4 + 1]);
            u.y = pack2(acc[mt][nt][2] + bias[mt * 4 + 2], acc[mt][nt][3] + bias[mt * 4 + 3]);
            *(uint2*)(xrow + (size_t)(p0 + nt * 16 + ln) * CLOI + wv * 32 + mt * 16 + q * 4) = u;
        }
}

// ---------------------------------------------------------------------------
// Prep kernel (unchanged)
// ---------------------------------------------------------------------------
__global__ __launch_bounds__(256) void prep_kernel(
    const float* __restrict__ conv1_w, const float* __restrict__ conv1_b,
    const float* __restrict__ bn2_g, const float* __restrict__ bn2_b,
    const float* __restrict__ bn2_m, const float* __restrict__ bn2_v,
    const float* __restrict__ conv2_w, const float* __restrict__ conv2_b,
    const float* __restrict__ bn3_g, const float* __restrict__ bn3_b,
    const float* __restrict__ bn3_m, const float* __restrict__ bn3_v,
    const float* __restrict__ conv3_w,
    const float* __restrict__ bn1_g, const float* __restrict__ bn1_b,
    const float* __restrict__ bn1_m, const float* __restrict__ bn1_v,
    const float* __restrict__ fc1_w,
    ushort* __restrict__ w1s, ushort* __restrict__ w2s, ushort* __restrict__ w3s,
    float* __restrict__ b1p, float* __restrict__ b2p,
    float* __restrict__ s1o, float* __restrict__ t1o,
    ushort* __restrict__ w0s)
{
    int idx = blockIdx.x * 256 + threadIdx.x;
    if (idx < 8192) {   // W1s [16kg][64m][8], fold s2
        int kg = idx >> 9, rem = idx & 511, m = rem >> 3, j = rem & 7;
        int c = kg * 8 + j;
        float s2 = bn2_g[m] * rsqrtf(bn2_v[m] + EPSV);
        w1s[idx] = f2bf(conv1_w[m * 128 + c] * s2);
    }
    if (idx < 12288) {  // W2s [3dt][8kg][64m][8], fold s3
        int dt = idx >> 12, rem = idx & 4095;
        int kg = rem >> 9, m = (rem >> 3) & 63, j = rem & 7;
        int i = kg * 8 + j;
        float s3 = bn3_g[m] * rsqrtf(bn3_v[m] + EPSV);
        w2s[idx] = f2bf(conv2_w[m * 192 + i * 3 + dt] * s3);
    }
    if (idx < 8192) {   // W3s [8kg][128m][8]
        int kg = idx >> 10, rem = idx & 1023, m = rem >> 3, j = rem & 7;
        w3s[idx] = f2bf(conv3_w[m * 64 + kg * 8 + j]);
    }
    if (idx < 32768) {  // W0s [32grp][128m][8] from fc1_w [128m][256c]
        int grp = idx >> 10, rem = idx & 1023, m = rem >> 3, j = rem & 7;
        w0s[idx] = f2bf(fc1_w[m * CIN + grp * 8 + j]);
    }
    if (idx < 64) {
        float s2 = bn2_g[idx] * rsqrtf(bn2_v[idx] + EPSV);
        b1p[idx] = conv1_b[idx] * s2 + bn2_b[idx] - bn2_m[idx] * s2;
        float s3 = bn3_g[idx] * rsqrtf(bn3_v[idx] + EPSV);
        b2p[idx] = conv2_b[idx] * s3 + bn3_b[idx] - bn3_m[idx] * s3;
    }
    if (idx < 128) {
        float s1 = bn1_g[idx] * rsqrtf(bn1_v[idx] + EPSV);
        s1o[idx] = s1;
        t1o[idx] = bn1_b[idx] - bn1_m[idx] * s1;
    }
}

// ---------------------------------------------------------------------------
// Fused kernel v4: dwordx2 gather, shuffle-free, half-wave point split.
// Clamps never collide (px in [-0.5,254.5] => ix0,iy0 in [0,254]), so the 4
// corners are always (ix0,iy0),(ix0,iy0+1),(ix0+1,iy0),(ix0+1,iy0+1) and the
// y-pairs are CONTIGUOUS 256 B rows.  Each lane loads uint2 (4 channels);
// lanes 0-31 process point jj, lanes 32-63 point jj+4 (one load inst serves
// two points).  Full 4-corner bilinear is computed IN-LANE for 4 channels —
// no cross-lane ops.  Each half owns exactly the pooled slot it writes
// (col = l*8 + 2*wv + half).  Per block: 512 load insts (was 1024), per-lane
// batch 16 x 8 B = 128 B in flight (2x v3).  __launch_bounds__(256,5):
// VGPR cap ~102 for the 32-reg batch; LDS 16K+8K(union)+1K ~= 25.6 KB.
// ---------------------------------------------------------------------------
__global__ __launch_bounds__(256, 5) void sample_head_kernel(
    const ushort* __restrict__ x, const float* __restrict__ lines,
    const ushort* __restrict__ w1s, const ushort* __restrict__ w2s,
    const ushort* __restrict__ w3s,
    const float* __restrict__ b1p, const float* __restrict__ b2p,
    const float* __restrict__ s1g, const float* __restrict__ t1g,
    const float* __restrict__ conv3_b,
    const float* __restrict__ fc2_w, const float* __restrict__ fc2_b,
    float* __restrict__ out)
{
    __shared__ ushort sH1[8192];             // 16 KB: h1, then xs (XOR-swizzled)
    __shared__ __align__(16) char sU[8192];  // 8 KB union: {sI 1K + sW2 2K} then sB2
    __shared__ float sB1[64], sB2b[64], sB3b[128];

    int*    sI  = (int*)sU;                  // [l*32 + j] base pixel i00
    float2* sW2 = (float2*)(sU + 1024);      // [l*32 + j] (wx0, wy0)
    ushort* sB2 = (ushort*)sU;               // [8kg][64col][8] (after gather)

    int tid = threadIdx.x;
    int wv = tid >> 6, lane = tid & 63;
    int q = lane >> 4, ln = lane & 15;
    int L0 = blockIdx.x * 8;
    int b = L0 / LL;                 // blocks never straddle images
    int colg = wv * 16 + ln;

    if (tid < 128) sB3b[tid] = conv3_b[tid];
    if (tid < 64)  { sB1[tid] = b1p[tid]; sB2b[tid] = b2p[tid]; }

    int half = lane >> 5;            // 0: points jj, 1: points jj+4
    int lc = lane & 31;              // channel quad: ch 4*lc .. 4*lc+3
    int kg = lc >> 1, j4 = (lc & 1) * 4;
    int swz = (kg & 7) << 3;         // ushort-index XOR swizzle

    // per-lane bn1 params for channels 4*lc..4*lc+3 (L1-resident)
    float4 s1v = *(const float4*)(s1g + lc * 4);
    float4 t1v = *(const float4*)(t1g + lc * 4);

    // ---- setup: 8 lines x 32 points, full 256-thread utilization ----
    {
        int l = tid >> 5, j = tid & 31;
        float lam = (float)j * (1.0f / 31.0f);
        const float* lp = lines + (size_t)(L0 + l) * 4;
        float e0x = lp[0], e0y = lp[1], e1x = lp[2], e1y = lp[3];
        float px = e0x * lam + e1x * (1.f - lam) - 0.5f;
        float py = e0y * lam + e1y * (1.f - lam) - 0.5f;
        float px0 = fminf(fmaxf(floorf(px), 0.f), 255.f);
        float py0 = fminf(fmaxf(floorf(py), 0.f), 255.f);
        int ix0 = (int)px0, iy0 = (int)py0;
        sI[l * 32 + j] = ix0 * WW + iy0;
        float2 w2; w2.x = px0 + 1.f - px; w2.y = py0 + 1.f - py;  // (wx0, wy0); wx1=1-wx0 exactly
        sW2[l * 32 + j] = w2;
    }
    __syncthreads();

    // ---- gather + maxpool: xs -> regs, h1 = relu(bn1(xs)) -> sH1 ----
    const uint2* xb2 = (const uint2*)(x + (size_t)b * HWP * CLOI);

    uint2 xsu[8];
#pragma unroll
    for (int l = 0; l < 8; l++) {
        // batch-issue 16 loads: 4 point-pairs x 4 corners (u2 = 4 channels)
        uint2 u[4][4];
        float2 wxy[4];
#pragma unroll
        for (int jj = 0; jj < 4; jj++) {
            int pt = l * 32 + wv * 8 + half * 4 + jj;
            int i00 = sI[pt];
            wxy[jj] = sW2[pt];
            const uint2* rp = xb2 + (size_t)((i00 << 5) + lc);
            u[jj][0] = rp[0];        // (ix0, iy0)
            u[jj][1] = rp[32];       // (ix0, iy0+1)
            u[jj][2] = rp[8192];     // (ix0+1, iy0)
            u[jj][3] = rp[8224];     // (ix0+1, iy0+1)
        }
        float p0v = -INFINITY, p1v = -INFINITY, p2v = -INFINITY, p3v = -INFINITY;
#pragma unroll
        for (int jj = 0; jj < 4; jj++) {
            float wx0 = wxy[jj].x, wy0 = wxy[jj].y;
            float w00 = wx0 * wy0;
            float w01 = wx0 - w00;           // wx0*(1-wy0)
            float w10 = wy0 - w00;           // (1-wx0)*wy0
            float w11 = 1.f - wx0 - wy0 + w00;
            float v0 = bf2f((ushort)(u[jj][0].x & 0xffff)) * w00 + bf2f((ushort)(u[jj][1].x & 0xffff)) * w01
                     + bf2f((ushort)(u[jj][2].x & 0xffff)) * w10 + bf2f((ushort)(u[jj][3].x & 0xffff)) * w11;
            float v1 = bf2f((ushort)(u[jj][0].x >> 16)) * w00 + bf2f((ushort)(u[jj][1].x >> 16)) * w01
                     + bf2f((ushort)(u[jj][2].x >> 16)) * w10 + bf2f((ushort)(u[jj][3].x >> 16)) * w11;
            float v2 = bf2f((ushort)(u[jj][0].y & 0xffff)) * w00 + bf2f((ushort)(u[jj][1].y & 0xffff)) * w01
                     + bf2f((ushort)(u[jj][2].y & 0xffff)) * w10 + bf2f((ushort)(u[jj][3].y & 0xffff)) * w11;
            float v3 = bf2f((ushort)(u[jj][0].y >> 16)) * w00 + bf2f((ushort)(u[jj][1].y >> 16)) * w01
                     + bf2f((ushort)(u[jj][2].y >> 16)) * w10 + bf2f((ushort)(u[jj][3].y >> 16)) * w11;
            p0v = fmaxf(p0v, v0); p1v = fmaxf(p1v, v1);
            p2v = fmaxf(p2v, v2); p3v = fmaxf(p3v, v3);
        }
        // xs (raw pooled) and h1 = relu(bn1(xs)) for this lane's 4 channels
        uint2 xv; xv.x = pack2(p0v, p1v); xv.y = pack2(p2v, p3v);
        xsu[l] = xv;
        float h0 = fmaxf(p0v * s1v.x + t1v.x, 0.f);
        float h1v = fmaxf(p1v * s1v.y + t1v.y, 0.f);
        float h2 = fmaxf(p2v * s1v.z + t1v.z, 0.f);
        float h3 = fmaxf(p3v * s1v.w + t1v.w, 0.f);
        uint2 hv; hv.x = pack2(h0, h1v); hv.y = pack2(h2, h3);
        int col = l * 8 + 2 * wv + half;
        int base = (kg * 64 + col) * 8 + j4;
        *(uint2*)(&sH1[base ^ swz]) = hv;
    }
    __syncthreads();   // gather done: sI/sW2 dead -> their bytes become sB2

    const short8 bzero = { 0, 0, 0, 0, 0, 0, 0, 0 };
    const f32x4 fzero = { 0.f, 0.f, 0.f, 0.f };

    // ---- conv1: M=64, K=128 (reads sH1 = h1) ----
    f32x4 acc1[4];
#pragma unroll
    for (int mt = 0; mt < 4; mt++) acc1[mt] = fzero;
#pragma unroll
    for (int ks = 0; ks < 4; ks++) {
        int kk = ks * 4 + q;
        short8 bfrag = *(short8*)(&sH1[((kk * 64 + colg) * 8) ^ ((kk & 7) << 3)]);
#pragma unroll
        for (int mt = 0; mt < 4; mt++) {
            short8 a = *(const short8*)(w1s + (kk * 64 + mt * 16 + ln) * 8);
            acc1[mt] = __builtin_amdgcn_mfma_f32_16x16x32_bf16(a, bfrag, acc1[mt], 0, 0, 0);
        }
    }
    // epilogue -> sB2 (linear; overwrites dead sI/sW2 bytes)
#pragma unroll
    for (int mt = 0; mt < 4; mt++) {
        int m0 = mt * 16 + q * 4;
        float v0 = fmaxf(acc1[mt][0] + sB1[m0 + 0], 0.f);
        float v1 = fmaxf(acc1[mt][1] + sB1[m0 + 1], 0.f);
        float v2 = fmaxf(acc1[mt][2] + sB1[m0 + 2], 0.f);
        float v3 = fmaxf(acc1[mt][3] + sB1[m0 + 3], 0.f);
        uint2 u; u.x = pack2(v0, v1); u.y = pack2(v2, v3);
        *(uint2*)(&sB2[((m0 >> 3) * 64 + colg) * 8 + (m0 & 7)]) = u;
    }
    __syncthreads();   // conv1 done: sH1 (h1) now dead, sB2 (conv1-out) live

    // ---- xs regs -> sH1 (same layout/swizzle the gather used) ----
#pragma unroll
    for (int l = 0; l < 8; l++) {
        int col = l * 8 + 2 * wv + half;
        int base = (kg * 64 + col) * 8 + j4;
        *(uint2*)(&sH1[base ^ swz]) = xsu[l];
    }

    // ---- conv2: preload all B-frags from sB2 (3 taps x 2 ks) ----
    int tpos = colg & 7;
    short8 bfr2[3][2];
#pragma unroll
    for (int dt = 0; dt < 3; dt++) {
        int tsh = tpos + dt - 1;
        bool valid = ((unsigned)tsh < 8u);
        int colr = colg + dt - 1;
        colr = colr < 0 ? 0 : (colr > 63 ? 63 : colr);
#pragma unroll
        for (int ks = 0; ks < 2; ks++) {
            short8 bfrag = *(short8*)(&sB2[((ks * 4 + q) * 64 + colr) * 8]);
            bfr2[dt][ks] = valid ? bfrag : bzero;
        }
    }
    __syncthreads();   // all sB2 reads drained; sB2 free for B3

    // ---- conv2 MFMAs, epilogue B3 -> sB2 (linear) ----
    f32x4 acc2[4];
#pragma unroll
    for (int mt = 0; mt < 4; mt++) acc2[mt] = fzero;
#pragma unroll
    for (int dt = 0; dt < 3; dt++)
#pragma unroll
        for (int ks = 0; ks < 2; ks++) {
            int kk = ks * 4 + q;
#pragma unroll
            for (int mt = 0; mt < 4; mt++) {
                short8 a = *(const short8*)(w2s + dt * 4096 + (kk * 64 + mt * 16 + ln) * 8);
                acc2[mt] = __builtin_amdgcn_mfma_f32_16x16x32_bf16(a, bfr2[dt][ks], acc2[mt], 0, 0, 0);
            }
        }
#pragma unroll
    for (int mt = 0; mt < 4; mt++) {
        int m0 = mt * 16 + q * 4;
        float v0 = fmaxf(acc2[mt][0] + sB2b[m0 + 0], 0.f);
        float v1 = fmaxf(acc2[mt][1] + sB2b[m0 + 1], 0.f);
        float v2 = fmaxf(acc2[mt][2] + sB2b[m0 + 2], 0.f);
        float v3 = fmaxf(acc2[mt][3] + sB2b[m0 + 3], 0.f);
        uint2 u; u.x = pack2(v0, v1); u.y = pack2(v2, v3);
        *(uint2*)(&sB2[((m0 >> 3) * 64 + colg) * 8 + (m0 & 7)]) = u;
    }
    __syncthreads();   // B3 live in sB2; xs live in sH1

    // ---- conv3: M=128, K=64 (reads B3 from sB2, linear) ----
    f32x4 acc3[8];
#pragma unroll
    for (int mt = 0; mt < 8; mt++) acc3[mt] = fzero;
#pragma unroll
    for (int ks = 0; ks < 2; ks++) {
        int kk = ks * 4 + q;
        short8 bfrag = *(short8*)(&sB2[(kk * 64 + colg) * 8]);
#pragma unroll
        for (int mt = 0; mt < 8; mt++) {
            short8 a = *(const short8*)(w3s + (kk * 128 + mt * 16 + ln) * 8);
            acc3[mt] = __builtin_amdgcn_mfma_f32_16x16x32_bf16(a, bfrag, acc3[mt], 0, 0, 0);
        }
    }

    // ---- residual + relu + fc2 (xs from sH1; fc2_w direct from L1) ----
    float p0 = 0.f, p1 = 0.f, p2 = 0.f;
#pragma unroll
    for (int mt = 0; mt < 8; mt++) {
#pragma unroll
        for (int r = 0; r < 4; r++) {
            int m = mt * 16 + q * 4 + r;
            int idx = ((m >> 3) * 512 + colg * 8 + (m & 7)) ^ (((m >> 3) & 7) << 3);
            float xsv = bf2f(sH1[idx]);
            float v = fmaxf(xsv + acc3[mt][r] + sB3b[m], 0.f);
            int fi = m * 8 + tpos;
            p0 += v * fc2_w[fi];
            p1 += v * fc2_w[1024 + fi];
            p2 += v * fc2_w[2048 + fi];
        }
    }
    p0 += __shfl_xor(p0, 32); p1 += __shfl_xor(p1, 32); p2 += __shfl_xor(p2, 32);
    p0 += __shfl_xor(p0, 16); p1 += __shfl_xor(p1, 16); p2 += __shfl_xor(p2, 16);
    p0 += __shfl_xor(p0, 4);  p1 += __shfl_xor(p1, 4);  p2 += __shfl_xor(p2, 4);
    p0 += __shfl_xor(p0, 2);  p1 += __shfl_xor(p1, 2);  p2 += __shfl_xor(p2, 2);
    p0 += __shfl_xor(p0, 1);  p1 += __shfl_xor(p1, 1);  p2 += __shfl_xor(p2, 1);

    if (lane == 0 || lane == 8) {
        int line = L0 + wv * 2 + (lane >> 3);
        out[(size_t)line * 3 + 0] = p0 + fc2_b[0];
        out[(size_t)line * 3 + 1] = p1 + fc2_b[1];
        out[(size_t)line * 3 + 2] = p2 + fc2_b[2];
    }
}

extern "C" void kernel_launch(void* const* d_in, const int* in_sizes, int n_in,
                              void* d_out, int out_size, void* d_ws, size_t ws_size,
                              hipStream_t stream) {
    const float* feature = (const float*)d_in[0];
    const float* lines   = (const float*)d_in[1];
    const float* fc1_w   = (const float*)d_in[2];
    const float* fc1_b   = (const float*)d_in[3];
    const float* bn1_g   = (const float*)d_in[4];
    const float* bn1_b   = (const float*)d_in[5];
    const float* bn1_m   = (const float*)d_in[6];
    const float* bn1_v   = (const float*)d_in[7];
    const float* conv1_w = (const float*)d_in[8];
    const float* conv1_b = (const float*)d_in[9];
    const float* bn2_g   = (const float*)d_in[10];
    const float* bn2_b   = (const float*)d_in[11];
    const float* bn2_m   = (const float*)d_in[12];
    const float* bn2_v   = (const float*)d_in[13];
    const float* conv2_w = (const float*)d_in[14];
    const float* conv2_b = (const float*)d_in[15];
    const float* bn3_g   = (const float*)d_in[16];
    const float* bn3_b   = (const float*)d_in[17];
    const float* bn3_m   = (const float*)d_in[18];
    const float* bn3_v   = (const float*)d_in[19];
    const float* conv3_w = (const float*)d_in[20];
    const float* conv3_b = (const float*)d_in[21];
    const float* fc2_w   = (const float*)d_in[22];
    const float* fc2_b   = (const float*)d_in[23];
    float* out = (float*)d_out;

    char* ws = (char*)d_ws;
    ushort* x_bf = (ushort*)ws;
    ushort* w1s  = (ushort*)(ws + W1S_OFF);
    ushort* w2s  = (ushort*)(ws + W2S_OFF);
    ushort* w3s  = (ushort*)(ws + W3S_OFF);
    float*  b1p  = (float*)(ws + B1P_OFF);
    float*  b2p  = (float*)(ws + B2P_OFF);
    float*  s1g  = (float*)(ws + S1_OFF);
    float*  t1g  = (float*)(ws + T1_OFF);
    ushort* w0s  = (ushort*)(ws + W0S_OFF);

    prep_kernel<<<128, 256, 0, stream>>>(
        conv1_w, conv1_b, bn2_g, bn2_b, bn2_m, bn2_v,
        conv2_w, conv2_b, bn3_g, bn3_b, bn3_m, bn3_v,
        conv3_w, bn1_g, bn1_b, bn1_m, bn1_v, fc1_w,
        w1s, w2s, w3s, b1p, b2p, s1g, t1g, w0s);
    fc1_kernel<<<2048, 256, 0, stream>>>(feature, w0s, fc1_b, x_bf);
    sample_head_kernel<<<BB * LL / 8, 256, 0, stream>>>(
        x_bf, lines, w1s, w2s, w3s, b1p, b2p, s1g, t1g, conv3_b, fc2_w, fc2_b, out);
}

// Round 6
// 288.113 us; speedup vs baseline: 1.0773x; 1.0064x over previous
//
#include <hip/hip_runtime.h>
#include <hip/hip_bf16.h>

// Problem constants
#define BB 2
#define LL 5000
#define CIN 256
#define CLOI 128
#define HH 256
#define WW 256
#define HWP (HH*WW)
#define NPTS0 32
#define NPTS1 8
#define PLANES 64
#define EPSV 1e-5f

// workspace layout (bytes)
#define X_BYTES   ((size_t)BB * HWP * CLOI * 2)            // 33,554,432: fc1 map bf16 channel-last
#define XS_BYTES  ((size_t)BB * LL * 1024 * 2)             // (dead region; offsets kept stable)
#define W1S_OFF   (X_BYTES + XS_BYTES)                     // 8192 bf16 = 16384 B   [16kg][64m][8]
#define W2S_OFF   (W1S_OFF + 16384)                        // 12288 bf16 = 24576 B  [3dt][8kg][64m][8]
#define W3S_OFF   (W2S_OFF + 24576)                        // 8192 bf16 = 16384 B   [8kg][128m][8]
#define B1P_OFF   (W3S_OFF + 16384)                        // 64 f32
#define B2P_OFF   (B1P_OFF + 256)                          // 64 f32
#define S1_OFF    (B2P_OFF + 256)                          // 128 f32
#define T1_OFF    (S1_OFF + 512)                           // 128 f32
#define W0S_OFF   (T1_OFF + 512)                           // fc1_w bf16 swizzled [32grp][128m][8] = 65536 B

typedef unsigned int uint;
typedef unsigned short ushort;
typedef __attribute__((ext_vector_type(8))) short short8;
typedef __attribute__((ext_vector_type(4))) float f32x4;

__device__ __forceinline__ float bf2f(ushort u) {
    uint v = ((uint)u) << 16;
    return __uint_as_float(v);
}
__device__ __forceinline__ ushort f2bf(float f) {
    uint x = __float_as_uint(f);
    uint r = (x + 0x7fffu + ((x >> 16) & 1u)) >> 16;   // RNE
    return (ushort)r;
}
__device__ __forceinline__ uint pack2(float a, float b) {
    return (uint)f2bf(a) | ((uint)f2bf(b) << 16);
}

// ---------------------------------------------------------------------------
// Kernel A: fc1 1x1 conv as bf16 MFMA GEMM.  (unchanged — memory-bound)
// ---------------------------------------------------------------------------
__global__ __launch_bounds__(256) void fc1_kernel(
    const float* __restrict__ feature, const ushort* __restrict__ w0s,
    const float* __restrict__ fc1_b, ushort* __restrict__ xout)
{
    __shared__ ushort sF[32 * 64 * 8];   // [grp(k/8)][px][j] bf16, 32 KB

    int tid = threadIdx.x;
    int tile = blockIdx.x;               // 0..2047
    int b = tile >> 10;
    int p0 = (tile & 1023) << 6;
    int wv = tid >> 6, lane = tid & 63;
    int q = lane >> 4, ln = lane & 15;

    // preload A-frags: afr[kg][mt], k = kg*32 + q*8 + j, m = wv*32 + mt*16 + ln
    short8 afr[8][2];
#pragma unroll
    for (int kg = 0; kg < 8; kg++)
#pragma unroll
        for (int mt = 0; mt < 2; mt++)
            afr[kg][mt] = *(const short8*)(w0s + ((size_t)((kg * 4 + q) * 128 + wv * 32 + mt * 16 + ln)) * 8);

    // stage feature tile -> bf16 LDS (B-frag layout)
    const float* fb = feature + (size_t)b * CIN * HWP + p0;
    int g_ = tid >> 4;                   // 0..15 (channel group within pass)
    int qd = tid & 15;                   // pixel quad
#pragma unroll
    for (int s = 0; s < 2; s++) {
        int g = s * 16 + g_;             // channel group 0..31 (8 ch each)
        const float* src = fb + (size_t)(g * 8) * HWP + qd * 4;
        float4 rv[8];
#pragma unroll
        for (int j = 0; j < 8; j++) rv[j] = *(const float4*)(src + (size_t)j * HWP);
#pragma unroll
        for (int i = 0; i < 4; i++) {
            uint4 u;
            u.x = pack2(((const float*)&rv[0])[i], ((const float*)&rv[1])[i]);
            u.y = pack2(((const float*)&rv[2])[i], ((const float*)&rv[3])[i]);
            u.z = pack2(((const float*)&rv[4])[i], ((const float*)&rv[5])[i]);
            u.w = pack2(((const float*)&rv[6])[i], ((const float*)&rv[7])[i]);
            *(uint4*)(&sF[(g * 64 + qd * 4 + i) * 8]) = u;
        }
    }
    __syncthreads();

    const f32x4 fzero = { 0.f, 0.f, 0.f, 0.f };
    f32x4 acc[2][4];
#pragma unroll
    for (int mt = 0; mt < 2; mt++)
#pragma unroll
        for (int nt = 0; nt < 4; nt++) acc[mt][nt] = fzero;

#pragma unroll
    for (int kg = 0; kg < 8; kg++) {
#pragma unroll
        for (int nt = 0; nt < 4; nt++) {
            short8 bfr = *(short8*)(&sF[((kg * 4 + q) * 64 + nt * 16 + ln) * 8]);
            acc[0][nt] = __builtin_amdgcn_mfma_f32_16x16x32_bf16(afr[kg][0], bfr, acc[0][nt], 0, 0, 0);
            acc[1][nt] = __builtin_amdgcn_mfma_f32_16x16x32_bf16(afr[kg][1], bfr, acc[1][nt], 0, 0, 0);
        }
    }

    // epilogue: bias + pack + store. o = wv*32 + mt*16 + q*4 + r, p = p0 + nt*16 + ln
    float bias[8];
    *(float4*)bias       = *(const float4*)(fc1_b + wv * 32 + q * 4);
    *(float4*)(bias + 4) = *(const float4*)(fc1_b + wv * 32 + 16 + q * 4);
    ushort* xrow = xout + (size_t)b * HWP * CLOI;
#pragma unroll
    for (int mt = 0; mt < 2; mt++)
#pragma unroll
        for (int nt = 0; nt < 4; nt++) {
            uint2 u;
            u.x = pack2(acc[mt][nt][0] + bias[mt * 4 + 0], acc[mt][nt][1] + bias[mt * 4 + 1]);
            u.y = pack2(acc[mt][nt][2] + bias[mt * 4 + 2], acc[mt][nt][3] + bias[mt * 4 + 3]);
            *(uint2*)(xrow + (size_t)(p0 + nt * 16 + ln) * CLOI + wv * 32 + mt * 16 + q * 4) = u;
        }
}

// ---------------------------------------------------------------------------
// Prep kernel (unchanged)
// ---------------------------------------------------------------------------
__global__ __launch_bounds__(256) void prep_kernel(
    const float* __restrict__ conv1_w, const float* __restrict__ conv1_b,
    const float* __restrict__ bn2_g, const float* __restrict__ bn2_b,
    const float* __restrict__ bn2_m, const float* __restrict__ bn2_v,
    const float* __restrict__ conv2_w, const float* __restrict__ conv2_b,
    const float* __restrict__ bn3_g, const float* __restrict__ bn3_b,
    const float* __restrict__ bn3_m, const float* __restrict__ bn3_v,
    const float* __restrict__ conv3_w,
    const float* __restrict__ bn1_g, const float* __restrict__ bn1_b,
    const float* __restrict__ bn1_m, const float* __restrict__ bn1_v,
    const float* __restrict__ fc1_w,
    ushort* __restrict__ w1s, ushort* __restrict__ w2s, ushort* __restrict__ w3s,
    float* __restrict__ b1p, float* __restrict__ b2p,
    float* __restrict__ s1o, float* __restrict__ t1o,
    ushort* __restrict__ w0s)
{
    int idx = blockIdx.x * 256 + threadIdx.x;
    if (idx < 8192) {   // W1s [16kg][64m][8], fold s2
        int kg = idx >> 9, rem = idx & 511, m = rem >> 3, j = rem & 7;
        int c = kg * 8 + j;
        float s2 = bn2_g[m] * rsqrtf(bn2_v[m] + EPSV);
        w1s[idx] = f2bf(conv1_w[m * 128 + c] * s2);
    }
    if (idx < 12288) {  // W2s [3dt][8kg][64m][8], fold s3
        int dt = idx >> 12, rem = idx & 4095;
        int kg = rem >> 9, m = (rem >> 3) & 63, j = rem & 7;
        int i = kg * 8 + j;
        float s3 = bn3_g[m] * rsqrtf(bn3_v[m] + EPSV);
        w2s[idx] = f2bf(conv2_w[m * 192 + i * 3 + dt] * s3);
    }
    if (idx < 8192) {   // W3s [8kg][128m][8]
        int kg = idx >> 10, rem = idx & 1023, m = rem >> 3, j = rem & 7;
        w3s[idx] = f2bf(conv3_w[m * 64 + kg * 8 + j]);
    }
    if (idx < 32768) {  // W0s [32grp][128m][8] from fc1_w [128m][256c]
        int grp = idx >> 10, rem = idx & 1023, m = rem >> 3, j = rem & 7;
        w0s[idx] = f2bf(fc1_w[m * CIN + grp * 8 + j]);
    }
    if (idx < 64) {
        float s2 = bn2_g[idx] * rsqrtf(bn2_v[idx] + EPSV);
        b1p[idx] = conv1_b[idx] * s2 + bn2_b[idx] - bn2_m[idx] * s2;
        float s3 = bn3_g[idx] * rsqrtf(bn3_v[idx] + EPSV);
        b2p[idx] = conv2_b[idx] * s3 + bn3_b[idx] - bn3_m[idx] * s3;
    }
    if (idx < 128) {
        float s1 = bn1_g[idx] * rsqrtf(bn1_v[idx] + EPSV);
        s1o[idx] = s1;
        t1o[idx] = bn1_b[idx] - bn1_m[idx] * s1;
    }
}

// ---------------------------------------------------------------------------
// Fused kernel v5: raw xs lives in sH1 the whole kernel; bn1+relu fused into
// conv1's fragment read (unpack-fma-relu-repack, ~50 VALU/ks — trivial vs the
// gather latency).  This deletes the xs-rematerialization phase + 16 xsu
// regs, which pays for a 2x deeper gather batch: 32 uint2 loads (256 B/lane)
// in flight before any consumption.  Phases:
//   setup -> barrier -> gather (xs -> sH1 swizzled) -> barrier ->
//   conv1 (sH1 + fused bn1 -> sB2) -> barrier -> conv2 preload -> barrier ->
//   conv2 MFMA -> sB2 -> barrier -> conv3 + residual(sH1) + fc2.
// LDS ~26.6 KB; __launch_bounds__(256,5) (VGPR cap ~102, gather live ~95).
// ---------------------------------------------------------------------------
__global__ __launch_bounds__(256, 5) void sample_head_kernel(
    const ushort* __restrict__ x, const float* __restrict__ lines,
    const ushort* __restrict__ w1s, const ushort* __restrict__ w2s,
    const ushort* __restrict__ w3s,
    const float* __restrict__ b1p, const float* __restrict__ b2p,
    const float* __restrict__ s1g, const float* __restrict__ t1g,
    const float* __restrict__ conv3_b,
    const float* __restrict__ fc2_w, const float* __restrict__ fc2_b,
    float* __restrict__ out)
{
    __shared__ ushort sH1[8192];             // 16 KB: raw xs (XOR-swizzled), permanent
    __shared__ __align__(16) char sU[8192];  // 8 KB union: {sI 1K + sW2 2K} then sB2
    __shared__ float sS1[128], sT1[128];     // bn1 scale/shift
    __shared__ float sB1[64], sB2b[64], sB3b[128];

    int*    sI  = (int*)sU;                  // [l*32 + j] base pixel i00
    float2* sW2 = (float2*)(sU + 1024);      // [l*32 + j] (wx0, wy0)
    ushort* sB2 = (ushort*)sU;               // [8kg][64col][8] (after gather)

    int tid = threadIdx.x;
    int wv = tid >> 6, lane = tid & 63;
    int q = lane >> 4, ln = lane & 15;
    int L0 = blockIdx.x * 8;
    int b = L0 / LL;                 // blocks never straddle images
    int colg = wv * 16 + ln;

    if (tid < 128) { sB3b[tid] = conv3_b[tid]; sS1[tid] = s1g[tid]; sT1[tid] = t1g[tid]; }
    if (tid < 64)  { sB1[tid] = b1p[tid]; sB2b[tid] = b2p[tid]; }

    int half = lane >> 5;            // 0: points jj, 1: points jj+4
    int lc = lane & 31;              // channel quad: ch 4*lc .. 4*lc+3
    int kg = lc >> 1, j4 = (lc & 1) * 4;
    int swz = (kg & 7) << 3;         // ushort-index XOR swizzle

    // ---- setup: 8 lines x 32 points, full 256-thread utilization ----
    {
        int l = tid >> 5, j = tid & 31;
        float lam = (float)j * (1.0f / 31.0f);
        const float* lp = lines + (size_t)(L0 + l) * 4;
        float e0x = lp[0], e0y = lp[1], e1x = lp[2], e1y = lp[3];
        float px = e0x * lam + e1x * (1.f - lam) - 0.5f;
        float py = e0y * lam + e1y * (1.f - lam) - 0.5f;
        float px0 = fminf(fmaxf(floorf(px), 0.f), 255.f);
        float py0 = fminf(fmaxf(floorf(py), 0.f), 255.f);
        int ix0 = (int)px0, iy0 = (int)py0;
        sI[l * 32 + j] = ix0 * WW + iy0;
        float2 w2; w2.x = px0 + 1.f - px; w2.y = py0 + 1.f - py;  // (wx0, wy0)
        sW2[l * 32 + j] = w2;
    }
    __syncthreads();

    // ---- gather + maxpool: xs (raw pooled) -> sH1, batch-2 pool groups ----
    const uint2* xb2 = (const uint2*)(x + (size_t)b * HWP * CLOI);

#pragma unroll
    for (int lp = 0; lp < 4; lp++) {
        // batch-issue 32 loads: 2 lines x 4 point-pairs x 4 corners
        uint2 u[2][4][4];
        float2 wxy[2][4];
#pragma unroll
        for (int h2 = 0; h2 < 2; h2++) {
#pragma unroll
            for (int jj = 0; jj < 4; jj++) {
                int pt = (lp * 2 + h2) * 32 + wv * 8 + half * 4 + jj;
                int i00 = sI[pt];
                wxy[h2][jj] = sW2[pt];
                const uint2* rp = xb2 + (size_t)((i00 << 5) + lc);
                u[h2][jj][0] = rp[0];        // (ix0, iy0)
                u[h2][jj][1] = rp[32];       // (ix0, iy0+1)
                u[h2][jj][2] = rp[8192];     // (ix0+1, iy0)
                u[h2][jj][3] = rp[8224];     // (ix0+1, iy0+1)
            }
        }
#pragma unroll
        for (int h2 = 0; h2 < 2; h2++) {
            float p0v = -INFINITY, p1v = -INFINITY, p2v = -INFINITY, p3v = -INFINITY;
#pragma unroll
            for (int jj = 0; jj < 4; jj++) {
                float wx0 = wxy[h2][jj].x, wy0 = wxy[h2][jj].y;
                float w00 = wx0 * wy0;
                float w01 = wx0 - w00;           // wx0*(1-wy0)
                float w10 = wy0 - w00;           // (1-wx0)*wy0
                float w11 = 1.f - wx0 - wy0 + w00;
                float v0 = bf2f((ushort)(u[h2][jj][0].x & 0xffff)) * w00 + bf2f((ushort)(u[h2][jj][1].x & 0xffff)) * w01
                         + bf2f((ushort)(u[h2][jj][2].x & 0xffff)) * w10 + bf2f((ushort)(u[h2][jj][3].x & 0xffff)) * w11;
                float v1 = bf2f((ushort)(u[h2][jj][0].x >> 16)) * w00 + bf2f((ushort)(u[h2][jj][1].x >> 16)) * w01
                         + bf2f((ushort)(u[h2][jj][2].x >> 16)) * w10 + bf2f((ushort)(u[h2][jj][3].x >> 16)) * w11;
                float v2 = bf2f((ushort)(u[h2][jj][0].y & 0xffff)) * w00 + bf2f((ushort)(u[h2][jj][1].y & 0xffff)) * w01
                         + bf2f((ushort)(u[h2][jj][2].y & 0xffff)) * w10 + bf2f((ushort)(u[h2][jj][3].y & 0xffff)) * w11;
                float v3 = bf2f((ushort)(u[h2][jj][0].y >> 16)) * w00 + bf2f((ushort)(u[h2][jj][1].y >> 16)) * w01
                         + bf2f((ushort)(u[h2][jj][2].y >> 16)) * w10 + bf2f((ushort)(u[h2][jj][3].y >> 16)) * w11;
                p0v = fmaxf(p0v, v0); p1v = fmaxf(p1v, v1);
                p2v = fmaxf(p2v, v2); p3v = fmaxf(p3v, v3);
            }
            uint2 xv; xv.x = pack2(p0v, p1v); xv.y = pack2(p2v, p3v);
            int col = (lp * 2 + h2) * 8 + 2 * wv + half;
            int base = (kg * 64 + col) * 8 + j4;
            *(uint2*)(&sH1[base ^ swz]) = xv;
        }
    }
    __syncthreads();   // gather done: sI/sW2 dead -> their bytes become sB2

    const short8 bzero = { 0, 0, 0, 0, 0, 0, 0, 0 };
    const f32x4 fzero = { 0.f, 0.f, 0.f, 0.f };

    // ---- conv1: M=64, K=128; B-frag = relu(bn1(xs)) computed on the fly ----
    f32x4 acc1[4];
#pragma unroll
    for (int mt = 0; mt < 4; mt++) acc1[mt] = fzero;
#pragma unroll
    for (int ks = 0; ks < 4; ks++) {
        int kk = ks * 4 + q;
        short8 xf = *(short8*)(&sH1[((kk * 64 + colg) * 8) ^ ((kk & 7) << 3)]);
        float s1r[8], t1r[8];
        *(float4*)(s1r)     = *(const float4*)(&sS1[kk * 8]);
        *(float4*)(s1r + 4) = *(const float4*)(&sS1[kk * 8 + 4]);
        *(float4*)(t1r)     = *(const float4*)(&sT1[kk * 8]);
        *(float4*)(t1r + 4) = *(const float4*)(&sT1[kk * 8 + 4]);
        uint hw[4];
#pragma unroll
        for (int p = 0; p < 4; p++) {
            float a = fmaxf(bf2f((ushort)xf[2 * p])     * s1r[2 * p]     + t1r[2 * p], 0.f);
            float c = fmaxf(bf2f((ushort)xf[2 * p + 1]) * s1r[2 * p + 1] + t1r[2 * p + 1], 0.f);
            hw[p] = pack2(a, c);
        }
        uint4 hv4; hv4.x = hw[0]; hv4.y = hw[1]; hv4.z = hw[2]; hv4.w = hw[3];
        short8 bfrag = *(short8*)&hv4;
#pragma unroll
        for (int mt = 0; mt < 4; mt++) {
            short8 a = *(const short8*)(w1s + (kk * 64 + mt * 16 + ln) * 8);
            acc1[mt] = __builtin_amdgcn_mfma_f32_16x16x32_bf16(a, bfrag, acc1[mt], 0, 0, 0);
        }
    }
    // epilogue -> sB2 (linear; overwrites dead sI/sW2 bytes)
#pragma unroll
    for (int mt = 0; mt < 4; mt++) {
        int m0 = mt * 16 + q * 4;
        float v0 = fmaxf(acc1[mt][0] + sB1[m0 + 0], 0.f);
        float v1 = fmaxf(acc1[mt][1] + sB1[m0 + 1], 0.f);
        float v2 = fmaxf(acc1[mt][2] + sB1[m0 + 2], 0.f);
        float v3 = fmaxf(acc1[mt][3] + sB1[m0 + 3], 0.f);
        uint2 u; u.x = pack2(v0, v1); u.y = pack2(v2, v3);
        *(uint2*)(&sB2[((m0 >> 3) * 64 + colg) * 8 + (m0 & 7)]) = u;
    }
    __syncthreads();   // conv1-out live in sB2; sH1 (xs) stays live

    // ---- conv2: preload all B-frags from sB2 (3 taps x 2 ks) ----
    int tpos = colg & 7;
    short8 bfr2[3][2];
#pragma unroll
    for (int dt = 0; dt < 3; dt++) {
        int tsh = tpos + dt - 1;
        bool valid = ((unsigned)tsh < 8u);
        int colr = colg + dt - 1;
        colr = colr < 0 ? 0 : (colr > 63 ? 63 : colr);
#pragma unroll
        for (int ks = 0; ks < 2; ks++) {
            short8 bfrag = *(short8*)(&sB2[((ks * 4 + q) * 64 + colr) * 8]);
            bfr2[dt][ks] = valid ? bfrag : bzero;
        }
    }
    __syncthreads();   // all sB2 reads drained; sB2 free for B3

    // ---- conv2 MFMAs, epilogue B3 -> sB2 (linear) ----
    f32x4 acc2[4];
#pragma unroll
    for (int mt = 0; mt < 4; mt++) acc2[mt] = fzero;
#pragma unroll
    for (int dt = 0; dt < 3; dt++)
#pragma unroll
        for (int ks = 0; ks < 2; ks++) {
            int kk = ks * 4 + q;
#pragma unroll
            for (int mt = 0; mt < 4; mt++) {
                short8 a = *(const short8*)(w2s + dt * 4096 + (kk * 64 + mt * 16 + ln) * 8);
                acc2[mt] = __builtin_amdgcn_mfma_f32_16x16x32_bf16(a, bfr2[dt][ks], acc2[mt], 0, 0, 0);
            }
        }
#pragma unroll
    for (int mt = 0; mt < 4; mt++) {
        int m0 = mt * 16 + q * 4;
        float v0 = fmaxf(acc2[mt][0] + sB2b[m0 + 0], 0.f);
        float v1 = fmaxf(acc2[mt][1] + sB2b[m0 + 1], 0.f);
        float v2 = fmaxf(acc2[mt][2] + sB2b[m0 + 2], 0.f);
        float v3 = fmaxf(acc2[mt][3] + sB2b[m0 + 3], 0.f);
        uint2 u; u.x = pack2(v0, v1); u.y = pack2(v2, v3);
        *(uint2*)(&sB2[((m0 >> 3) * 64 + colg) * 8 + (m0 & 7)]) = u;
    }
    __syncthreads();   // B3 live in sB2; xs live in sH1

    // ---- conv3: M=128, K=64 (reads B3 from sB2, linear) ----
    f32x4 acc3[8];
#pragma unroll
    for (int mt = 0; mt < 8; mt++) acc3[mt] = fzero;
#pragma unroll
    for (int ks = 0; ks < 2; ks++) {
        int kk = ks * 4 + q;
        short8 bfrag = *(short8*)(&sB2[(kk * 64 + colg) * 8]);
#pragma unroll
        for (int mt = 0; mt < 8; mt++) {
            short8 a = *(const short8*)(w3s + (kk * 128 + mt * 16 + ln) * 8);
            acc3[mt] = __builtin_amdgcn_mfma_f32_16x16x32_bf16(a, bfrag, acc3[mt], 0, 0, 0);
        }
    }

    // ---- residual + relu + fc2 (xs from sH1; fc2_w direct from L1) ----
    float p0 = 0.f, p1 = 0.f, p2 = 0.f;
#pragma unroll
    for (int mt = 0; mt < 8; mt++) {
#pragma unroll
        for (int r = 0; r < 4; r++) {
            int m = mt * 16 + q * 4 + r;
            int idx = ((m >> 3) * 512 + colg * 8 + (m & 7)) ^ (((m >> 3) & 7) << 3);
            float xsv = bf2f(sH1[idx]);
            float v = fmaxf(xsv + acc3[mt][r] + sB3b[m], 0.f);
            int fi = m * 8 + tpos;
            p0 += v * fc2_w[fi];
            p1 += v * fc2_w[1024 + fi];
            p2 += v * fc2_w[2048 + fi];
        }
    }
    p0 += __shfl_xor(p0, 32); p1 += __shfl_xor(p1, 32); p2 += __shfl_xor(p2, 32);
    p0 += __shfl_xor(p0, 16); p1 += __shfl_xor(p1, 16); p2 += __shfl_xor(p2, 16);
    p0 += __shfl_xor(p0, 4);  p1 += __shfl_xor(p1, 4);  p2 += __shfl_xor(p2, 4);
    p0 += __shfl_xor(p0, 2);  p1 += __shfl_xor(p1, 2);  p2 += __shfl_xor(p2, 2);
    p0 += __shfl_xor(p0, 1);  p1 += __shfl_xor(p1, 1);  p2 += __shfl_xor(p2, 1);

    if (lane == 0 || lane == 8) {
        int line = L0 + wv * 2 + (lane >> 3);
        out[(size_t)line * 3 + 0] = p0 + fc2_b[0];
        out[(size_t)line * 3 + 1] = p1 + fc2_b[1];
        out[(size_t)line * 3 + 2] = p2 + fc2_b[2];
    }
}

extern "C" void kernel_launch(void* const* d_in, const int* in_sizes, int n_in,
                              void* d_out, int out_size, void* d_ws, size_t ws_size,
                              hipStream_t stream) {
    const float* feature = (const float*)d_in[0];
    const float* lines   = (const float*)d_in[1];
    const float* fc1_w   = (const float*)d_in[2];
    const float* fc1_b   = (const float*)d_in[3];
    const float* bn1_g   = (const float*)d_in[4];
    const float* bn1_b   = (const float*)d_in[5];
    const float* bn1_m   = (const float*)d_in[6];
    const float* bn1_v   = (const float*)d_in[7];
    const float* conv1_w = (const float*)d_in[8];
    const float* conv1_b = (const float*)d_in[9];
    const float* bn2_g   = (const float*)d_in[10];
    const float* bn2_b   = (const float*)d_in[11];
    const float* bn2_m   = (const float*)d_in[12];
    const float* bn2_v   = (const float*)d_in[13];
    const float* conv2_w = (const float*)d_in[14];
    const float* conv2_b = (const float*)d_in[15];
    const float* bn3_g   = (const float*)d_in[16];
    const float* bn3_b   = (const float*)d_in[17];
    const float* bn3_m   = (const float*)d_in[18];
    const float* bn3_v   = (const float*)d_in[19];
    const float* conv3_w = (const float*)d_in[20];
    const float* conv3_b = (const float*)d_in[21];
    const float* fc2_w   = (const float*)d_in[22];
    const float* fc2_b   = (const float*)d_in[23];
    float* out = (float*)d_out;

    char* ws = (char*)d_ws;
    ushort* x_bf = (ushort*)ws;
    ushort* w1s  = (ushort*)(ws + W1S_OFF);
    ushort* w2s  = (ushort*)(ws + W2S_OFF);
    ushort* w3s  = (ushort*)(ws + W3S_OFF);
    float*  b1p  = (float*)(ws + B1P_OFF);
    float*  b2p  = (float*)(ws + B2P_OFF);
    float*  s1g  = (float*)(ws + S1_OFF);
    float*  t1g  = (float*)(ws + T1_OFF);
    ushort* w0s  = (ushort*)(ws + W0S_OFF);

    prep_kernel<<<128, 256, 0, stream>>>(
        conv1_w, conv1_b, bn2_g, bn2_b, bn2_m, bn2_v,
        conv2_w, conv2_b, bn3_g, bn3_b, bn3_m, bn3_v,
        conv3_w, bn1_g, bn1_b, bn1_m, bn1_v, fc1_w,
        w1s, w2s, w3s, b1p, b2p, s1g, t1g, w0s);
    fc1_kernel<<<2048, 256, 0, stream>>>(feature, w0s, fc1_b, x_bf);
    sample_head_kernel<<<BB * LL / 8, 256, 0, stream>>>(
        x_bf, lines, w1s, w2s, w3s, b1p, b2p, s1g, t1g, conv3_b, fc2_w, fc2_b, out);
}